// Round 7
// baseline (228.352 us; speedup 1.0000x reference)
//
#include <hip/hip_runtime.h>
#include <hip/hip_bf16.h>

#define NWIN 2048
#define LOG2E 1.44269504f
#define QSCALE 0.36067376f   // 0.25 * log2(e)

// ws layout (float offsets)
#define OFF_AFF 0        // 512 floats: [b][0..127]=softplus(scale), [128..255]=bias
#define OFF_RPB 512      // 32768 floats: rpb[h][row][col] * LOG2E  (natural, float4-loadable)
#define OFF_WQ  33280    // 49152 bf16 (24576 floats): qkv_w packed frags (16x16x32)
#define OFF_WP  57856    // 16384 bf16 (8192 floats): proj_w packed B-frags (16x16x16)

typedef __attribute__((ext_vector_type(8))) __bf16 bf16x8;
typedef __attribute__((ext_vector_type(4))) float floatx4;
typedef __attribute__((ext_vector_type(4))) short short4v;

#if __has_builtin(__builtin_amdgcn_exp2f)
#define EXP2F __builtin_amdgcn_exp2f
#else
#define EXP2F exp2f
#endif

__global__ __launch_bounds__(256) void prep_kernel(
    const float* __restrict__ frame_type, const float* __restrict__ qkv_w,
    const float* __restrict__ table, const float* __restrict__ proj_w,
    const float* __restrict__ aff_w1, const float* __restrict__ aff_b1,
    const float* __restrict__ aff_w2, const int* __restrict__ rel_index,
    float* __restrict__ ws)
{
  const int gid = blockIdx.x * 256 + threadIdx.x;   // grid covers 49152
  // pack qkv_w into 16x16x32 frag order: idx = ((nt*4+kt)*64+lane)*8+j
  if (gid < 49152) {
    int j = gid & 7, lane = (gid >> 3) & 63, kt = (gid >> 9) & 3, nt = gid >> 11;
    int n = nt * 16 + (lane & 15);
    int k = kt * 32 + (lane >> 4) * 8 + j;
    ((__bf16*)(ws + OFF_WQ))[gid] = (__bf16)qkv_w[n * 128 + k];
  }
  // pack proj_w into 16x16x16 B-frag order: idx = ((h*8+nt)*64+lane)*4+j
  if (gid < 16384) {
    int j = gid & 3, lane = (gid >> 2) & 63, nt = (gid >> 8) & 7, h = gid >> 11;
    int n = nt * 16 + (lane & 15);
    int k = h * 16 + (lane >> 4) * 4 + j;
    ((__bf16*)(ws + OFF_WP))[gid] = (__bf16)proj_w[n * 128 + k];
  }
  // rpb natural [h][row][col] layout, pre-scaled by log2(e)
  if (gid < 32768) {
    int h = gid >> 12, rem = gid & 4095;
    ws[OFF_RPB + gid] = table[rel_index[rem] * 8 + h] * LOG2E;
  }
  // affine params
  if (gid < 512) {
    int b = gid >> 8, c2 = gid & 255;
    float hd[16];
    #pragma unroll
    for (int j = 0; j < 16; ++j) {
      float t = frame_type[b*2+0]*aff_w1[j*2+0] + frame_type[b*2+1]*aff_w1[j*2+1] + aff_b1[j];
      hd[j] = 1.0f / (1.0f + expf(-t));
    }
    float ap = 0.f;
    #pragma unroll
    for (int j = 0; j < 16; ++j) ap += hd[j] * aff_w2[c2*16 + j];
    float r = (c2 < 128) ? ((ap > 20.f) ? ap : log1pf(expf(ap))) : ap;
    ws[OFF_AFF + gid] = r;
  }
}

// Swapped-QK^T structure (validated round 3):
//   S^T = mfma(K_slot, Q^T): lane holds S[q=row0+l15][j=sigma(jt,quad,r)]
//   sigma(jt,quad,r) = 32*(jt&1) + 8*quad + 4*(jt>>1) + r
//   K sigma-permuted in sK; V^T natural; exp2'd scores pack IN-LANE into the
//   PV B-frag; Q^T per-wave in registers. One barrier, LDS 32768 B.
// Round-7 changes:
//   (1) sK swizzle FIX: pitch-128 makes bank index row-independent (256B ≡ 0
//       mod 128), and ((row&7)<<4) only injects 2 usable bank bits -> kb reads
//       were 4-way (round-6 conflicts UP 1.31M->4.19M). New swizzle injects
//       the 3rd bit at col bit-2: col ^ ((row&3)<<4) ^ (row&4) -> 2-way,
//       8B-read alignment preserved.
//   (2) PAIRED-HEAD ILP: process heads (2h, 2h+1) per iteration as two fully
//       independent register chains (QK/exp2/PV/proj both in one BB). Six
//       rounds showed every pipe <35% with ~3 waves/SIMD: dependency-stall
//       bound. Round-4 (loads-only pipelining) gave the scheduler nothing to
//       overlap; full-body pairing does. Est. peak live ~125 regs < 170 cap.
// Occupancy is NOT the lever: achieved occupancy invariant (28.6/29.5/29.3)
//   across 3/4/5-block static LDS limits (rounds 0/3/6).
// launch_bounds (256,3): cap 170. Tripwires: WRITE_SIZE == 65536 KB (spill),
//   VGPR should RISE to ~110-140 (pairing materialized; ~84 = serialized).
__global__ __launch_bounds__(256, 3) void attn_kernel(
    const float* __restrict__ x, const float* __restrict__ mask,
    const float* __restrict__ qkv_b, const float* __restrict__ proj_b,
    const float* __restrict__ ws, float* __restrict__ out)
{
  __shared__ __attribute__((aligned(16))) __bf16 sK [64 * 128];  // 16384 B, swizzled
  __shared__ __attribute__((aligned(16))) __bf16 sVT[128 * 64];  // 16384 B, swizzled
  // total 32768 B

#define SKI(row, col) ((row)*128 + ((col) ^ (((row)&3)<<4) ^ ((row)&4)))
#define SVI(ch, tok)  ((ch)*64  + ((tok) ^ (((ch)&7)<<3)))

  const int w    = blockIdx.x;
  const int b    = w >> 10;
  const int tid  = threadIdx.x;
  const int wv   = tid >> 6;
  const int lane = tid & 63;
  const int quad = lane >> 4;
  const int l15  = lane & 15;
  const int row0 = wv * 16;

  // ---- A/B-fragments of x from global (fp32 -> bf16) ----
  bf16x8 af[4][4];   // [mt][kt]
  {
    const float* xw = x + (size_t)w * 8192;
    #pragma unroll
    for (int mt = 0; mt < 4; ++mt)
      #pragma unroll
      for (int kt = 0; kt < 4; ++kt) {
        const float* p = xw + (mt*16 + l15) * 128 + kt*32 + quad*8;
        float4 f0 = *(const float4*)p;
        float4 f1 = *(const float4*)(p + 4);
        bf16x8 v;
        v[0]=(__bf16)f0.x; v[1]=(__bf16)f0.y; v[2]=(__bf16)f0.z; v[3]=(__bf16)f0.w;
        v[4]=(__bf16)f1.x; v[5]=(__bf16)f1.y; v[6]=(__bf16)f1.z; v[7]=(__bf16)f1.w;
        af[mt][kt] = v;
      }
  }

  const __bf16* wq = (const __bf16*)(ws + OFF_WQ);

  // ---- K,V slices: wave handles nt in {8+wv, 12+wv, 16+wv, 20+wv} over all mt ----
  {
    #pragma unroll
    for (int t = 0; t < 4; ++t) {
      const int nt = 8 + ((t >> 1) << 3) + ((t & 1) << 2) + wv;
      bf16x8 bfr[4];
      #pragma unroll
      for (int kt = 0; kt < 4; ++kt)
        bfr[kt] = *(const bf16x8*)(wq + ((size_t)(nt*4 + kt) * 64 + lane) * 8);
      const float bias = qkv_b[nt*16 + l15];
      const int col = nt*16 + l15;
      #pragma unroll
      for (int mt = 0; mt < 4; ++mt) {
        floatx4 acc = {bias, bias, bias, bias};
        #pragma unroll
        for (int kt = 0; kt < 4; ++kt)
          acc = __builtin_amdgcn_mfma_f32_16x16x32_bf16(af[mt][kt], bfr[kt], acc, 0, 0, 0);
        if (nt < 16) {          // K: sigma-permuted row placement, swizzled
          const int c = col - 128;
          const int srow0 = ((((quad & 1) << 1) + (mt >> 1)) << 4)
                          + ((((mt & 1) << 1) | (quad >> 1)) << 2);
          #pragma unroll
          for (int r = 0; r < 4; ++r) sK[SKI(srow0 + r, c)] = (__bf16)acc[r];
        } else {                // V, modulated, transposed (natural token order), swizzled
          const int c = col - 256;
          const float sp = ws[OFF_AFF + b*256 + c];
          const float bp = ws[OFF_AFF + b*256 + 128 + c];
          const int rowb = mt*16 + quad*4;
          #pragma unroll
          for (int r = 0; r < 4; ++r) sVT[SVI(c, rowb + r)] = (__bf16)fmaf(sp, acc[r], bp);
        }
      }
    }
  }

  // ---- Q^T GEMM into registers: own 16 tokens, all 8 head-slices ----
  bf16x8 aq[4];
  #pragma unroll
  for (int kt = 0; kt < 4; ++kt) aq[kt] = af[0][kt];
  #pragma unroll
  for (int mt = 1; mt < 4; ++mt)
    if (wv == mt) {
      #pragma unroll
      for (int kt = 0; kt < 4; ++kt) aq[kt] = af[mt][kt];
    }

  short4v qa[8];   // qa[h] = B-frag: Q[row0+l15][h*16+quad*4+j] * QSCALE
  {
    #pragma unroll
    for (int nt = 0; nt < 8; ++nt) {
      bf16x8 bfr[4];
      #pragma unroll
      for (int kt = 0; kt < 4; ++kt)
        bfr[kt] = *(const bf16x8*)(wq + ((size_t)(nt*4 + kt) * 64 + lane) * 8);
      floatx4 acc = *(const floatx4*)(qkv_b + nt*16 + quad*4);
      #pragma unroll
      for (int kt = 0; kt < 4; ++kt)
        acc = __builtin_amdgcn_mfma_f32_16x16x32_bf16(bfr[kt], aq[kt], acc, 0, 0, 0);
      union { short4v s; __bf16 h4[4]; } u;
      #pragma unroll
      for (int r = 0; r < 4; ++r) u.h4[r] = (__bf16)(acc[r] * QSCALE);
      qa[nt] = u.s;
    }
  }
  __syncthreads();   // the only barrier

  // ---- mask hoist (pre-scaled by log2e), float4 over r at sigma j-offsets ----
  floatx4 mv[4];
  {
    const float* mrow = mask + (size_t)(w & 1023) * 4096 + (row0 + l15) * 64;
    #pragma unroll
    for (int jt = 0; jt < 4; ++jt) {
      const int joff = ((jt & 1) << 5) + ((jt >> 1) << 2) + (quad << 3);
      floatx4 m4 = *(const floatx4*)(mrow + joff);
      #pragma unroll
      for (int r = 0; r < 4; ++r) mv[jt][r] = m4[r] * LOG2E;
    }
  }

  floatx4 pacc[8];
  #pragma unroll
  for (int nt = 0; nt < 8; ++nt) {
    float pb = proj_b[nt*16 + l15];
    pacc[nt] = (floatx4){pb, pb, pb, pb};
  }

  bf16x8 ones;
  #pragma unroll
  for (int i = 0; i < 8; ++i) ones[i] = (__bf16)1.0f;

  const float* rpb = ws + OFF_RPB;
  const __bf16* wp = (const __bf16*)(ws + OFF_WP);

  // ---- paired-head loop: two independent chains per iteration ----
  #pragma unroll 1
  for (int hh = 0; hh < 4; ++hh) {
    const int h0 = hh * 2;
    const int h1 = h0 + 1;

    // loads for both heads
    floatx4 rq0[4], rq1[4];
    short4v kb0[4], kb1[4];
    #pragma unroll
    for (int jt = 0; jt < 4; ++jt) {
      const int joff = ((jt & 1) << 5) + ((jt >> 1) << 2) + (quad << 3);
      rq0[jt] = *(const floatx4*)(rpb + h0*4096 + (row0 + l15)*64 + joff);
      rq1[jt] = *(const floatx4*)(rpb + h1*4096 + (row0 + l15)*64 + joff);
      kb0[jt] = *(const short4v*)(&sK[SKI(jt*16 + l15, h0*16 + quad*4)]);
      kb1[jt] = *(const short4v*)(&sK[SKI(jt*16 + l15, h1*16 + quad*4)]);
    }

    // QK^T both heads (independent chains)
    floatx4 s0[4], s1[4];
    #pragma unroll
    for (int jt = 0; jt < 4; ++jt) {
      floatx4 ci0 = rq0[jt] + mv[jt];
      floatx4 ci1 = rq1[jt] + mv[jt];
      s0[jt] = __builtin_amdgcn_mfma_f32_16x16x16bf16_1k(kb0[jt], qa[h0], ci0, 0, 0, 0);
      s1[jt] = __builtin_amdgcn_mfma_f32_16x16x16bf16_1k(kb1[jt], qa[h1], ci1, 0, 0, 0);
    }

    // exp2 + in-lane pack, both heads
    union { bf16x8 v; __bf16 e[8]; } p00, p01, p10, p11;
    #pragma unroll
    for (int r = 0; r < 4; ++r) {
      p00.e[r]     = (__bf16)EXP2F(s0[0][r]);
      p00.e[4 + r] = (__bf16)EXP2F(s0[2][r]);
      p01.e[r]     = (__bf16)EXP2F(s0[1][r]);
      p01.e[4 + r] = (__bf16)EXP2F(s0[3][r]);
      p10.e[r]     = (__bf16)EXP2F(s1[0][r]);
      p10.e[4 + r] = (__bf16)EXP2F(s1[2][r]);
      p11.e[r]     = (__bf16)EXP2F(s1[1][r]);
      p11.e[4 + r] = (__bf16)EXP2F(s1[3][r]);
    }

    // PV + rowsum, both heads
    bf16x8 vb00 = *(const bf16x8*)(&sVT[SVI(h0*16 + l15, quad*8)]);
    bf16x8 vb01 = *(const bf16x8*)(&sVT[SVI(h0*16 + l15, 32 + quad*8)]);
    bf16x8 vb10 = *(const bf16x8*)(&sVT[SVI(h1*16 + l15, quad*8)]);
    bf16x8 vb11 = *(const bf16x8*)(&sVT[SVI(h1*16 + l15, 32 + quad*8)]);
    floatx4 o20 = {0.f,0.f,0.f,0.f}, sm0 = {0.f,0.f,0.f,0.f};
    floatx4 o21 = {0.f,0.f,0.f,0.f}, sm1 = {0.f,0.f,0.f,0.f};
    o20 = __builtin_amdgcn_mfma_f32_16x16x32_bf16(vb00, p00.v, o20, 0, 0, 0);
    o21 = __builtin_amdgcn_mfma_f32_16x16x32_bf16(vb10, p10.v, o21, 0, 0, 0);
    sm0 = __builtin_amdgcn_mfma_f32_16x16x32_bf16(ones, p00.v, sm0, 0, 0, 0);
    sm1 = __builtin_amdgcn_mfma_f32_16x16x32_bf16(ones, p10.v, sm1, 0, 0, 0);
    o20 = __builtin_amdgcn_mfma_f32_16x16x32_bf16(vb01, p01.v, o20, 0, 0, 0);
    o21 = __builtin_amdgcn_mfma_f32_16x16x32_bf16(vb11, p11.v, o21, 0, 0, 0);
    sm0 = __builtin_amdgcn_mfma_f32_16x16x32_bf16(ones, p01.v, sm0, 0, 0, 0);
    sm1 = __builtin_amdgcn_mfma_f32_16x16x32_bf16(ones, p11.v, sm1, 0, 0, 0);

    // normalize + proj, both heads
    short4v wpf0[8], wpf1[8];
    #pragma unroll
    for (int nt = 0; nt < 8; ++nt) {
      wpf0[nt] = *(const short4v*)(wp + ((size_t)(h0*8 + nt)*64 + lane)*4);
      wpf1[nt] = *(const short4v*)(wp + ((size_t)(h1*8 + nt)*64 + lane)*4);
    }
    const float inv0 = 1.0f / sm0[0];
    const float inv1 = 1.0f / sm1[0];
    union { short4v s; __bf16 hh_[4]; } u0, u1;
    #pragma unroll
    for (int r = 0; r < 4; ++r) {
      u0.hh_[r] = (__bf16)(o20[r] * inv0);
      u1.hh_[r] = (__bf16)(o21[r] * inv1);
    }
    #pragma unroll
    for (int nt = 0; nt < 8; ++nt) {
      pacc[nt] = __builtin_amdgcn_mfma_f32_16x16x16bf16_1k(u0.s, wpf0[nt], pacc[nt], 0, 0, 0);
      pacc[nt] = __builtin_amdgcn_mfma_f32_16x16x16bf16_1k(u1.s, wpf1[nt], pacc[nt], 0, 0, 0);
    }
  }

  // ---- store ----
  {
    float* ow = out + (size_t)w * 8192;
    #pragma unroll
    for (int nt = 0; nt < 8; ++nt)
      #pragma unroll
      for (int r = 0; r < 4; ++r)
        ow[(row0 + quad*4 + r)*128 + nt*16 + l15] = pacc[nt][r];
  }
#undef SKI
#undef SVI
}

extern "C" void kernel_launch(void* const* d_in, const int* in_sizes, int n_in,
                              void* d_out, int out_size, void* d_ws, size_t ws_size,
                              hipStream_t stream)
{
  const float* x          = (const float*)d_in[0];
  const float* mask       = (const float*)d_in[1];
  const float* frame_type = (const float*)d_in[2];
  const float* qkv_w      = (const float*)d_in[3];
  const float* qkv_b      = (const float*)d_in[4];
  const float* table      = (const float*)d_in[5];
  const float* proj_w     = (const float*)d_in[6];
  const float* proj_b     = (const float*)d_in[7];
  const float* aff_w1     = (const float*)d_in[8];
  const float* aff_b1     = (const float*)d_in[9];
  const float* aff_w2     = (const float*)d_in[10];
  const int*   rel_index  = (const int*)d_in[11];
  float* ws   = (float*)d_ws;
  float* outp = (float*)d_out;

  prep_kernel<<<192, 256, 0, stream>>>(frame_type, qkv_w, table, proj_w,
                                       aff_w1, aff_b1, aff_w2, rel_index, ws);
  attn_kernel<<<NWIN, 256, 0, stream>>>(x, mask, qkv_b, proj_b, ws, outp);
}

// Round 8
// 223.894 us; speedup vs baseline: 1.0199x; 1.0199x over previous
//
#include <hip/hip_runtime.h>
#include <hip/hip_bf16.h>

#define NWIN 2048
#define LOG2E 1.44269504f
#define QSCALE 0.36067376f   // 0.25 * log2(e)

// ws layout (float offsets)
#define OFF_AFF 0        // 512 floats: [b][0..127]=softplus(scale), [128..255]=bias
#define OFF_RPB 512      // 32768 floats: rpb[h][row][col] * LOG2E  (natural, float4-loadable)
#define OFF_WQ  33280    // 49152 bf16 (24576 floats): qkv_w packed frags (16x16x32)
#define OFF_WP  57856    // 16384 bf16 (8192 floats): proj_w packed B-frags (16x16x16)

typedef __attribute__((ext_vector_type(8))) __bf16 bf16x8;
typedef __attribute__((ext_vector_type(4))) float floatx4;
typedef __attribute__((ext_vector_type(4))) short short4v;

#if __has_builtin(__builtin_amdgcn_exp2f)
#define EXP2F __builtin_amdgcn_exp2f
#else
#define EXP2F exp2f
#endif

__global__ __launch_bounds__(256) void prep_kernel(
    const float* __restrict__ frame_type, const float* __restrict__ qkv_w,
    const float* __restrict__ table, const float* __restrict__ proj_w,
    const float* __restrict__ aff_w1, const float* __restrict__ aff_b1,
    const float* __restrict__ aff_w2, const int* __restrict__ rel_index,
    float* __restrict__ ws)
{
  const int gid = blockIdx.x * 256 + threadIdx.x;   // grid covers 49152
  // pack qkv_w into 16x16x32 frag order: idx = ((nt*4+kt)*64+lane)*8+j
  if (gid < 49152) {
    int j = gid & 7, lane = (gid >> 3) & 63, kt = (gid >> 9) & 3, nt = gid >> 11;
    int n = nt * 16 + (lane & 15);
    int k = kt * 32 + (lane >> 4) * 8 + j;
    ((__bf16*)(ws + OFF_WQ))[gid] = (__bf16)qkv_w[n * 128 + k];
  }
  // pack proj_w into 16x16x16 B-frag order: idx = ((h*8+nt)*64+lane)*4+j
  if (gid < 16384) {
    int j = gid & 3, lane = (gid >> 2) & 63, nt = (gid >> 8) & 7, h = gid >> 11;
    int n = nt * 16 + (lane & 15);
    int k = h * 16 + (lane >> 4) * 4 + j;
    ((__bf16*)(ws + OFF_WP))[gid] = (__bf16)proj_w[n * 128 + k];
  }
  // rpb natural [h][row][col] layout, pre-scaled by log2(e)
  if (gid < 32768) {
    int h = gid >> 12, rem = gid & 4095;
    ws[OFF_RPB + gid] = table[rel_index[rem] * 8 + h] * LOG2E;
  }
  // affine params
  if (gid < 512) {
    int b = gid >> 8, c2 = gid & 255;
    float hd[16];
    #pragma unroll
    for (int j = 0; j < 16; ++j) {
      float t = frame_type[b*2+0]*aff_w1[j*2+0] + frame_type[b*2+1]*aff_w1[j*2+1] + aff_b1[j];
      hd[j] = 1.0f / (1.0f + expf(-t));
    }
    float ap = 0.f;
    #pragma unroll
    for (int j = 0; j < 16; ++j) ap += hd[j] * aff_w2[c2*16 + j];
    float r = (c2 < 128) ? ((ap > 20.f) ? ap : log1pf(expf(ap))) : ap;
    ws[OFF_AFF + gid] = r;
  }
}

// Swapped-QK^T structure (validated round 3):
//   S^T = mfma(K_slot, Q^T): lane holds S[q=row0+l15][j=sigma(jt,quad,r)]
//   sigma(jt,quad,r) = 32*(jt&1) + 8*quad + 4*(jt>>1) + r
//   K sigma-permuted in sK; V^T natural; exp2'd scores pack IN-LANE into the
//   PV B-frag; Q^T per-wave in registers. One barrier, LDS 32768 B.
// Round-8 change: 2-deep head pipeline PINNED with sched_barrier(0).
//   Rounds 4/7 proved the pre-RA scheduler sinks independent prefetches /
//   serializes paired chains to minimize pressure (VGPR stuck at 84 both
//   times). sched_barrier(0) fences make that motion illegal: HLOAD(h+1)
//   is forced above HCOMP(h), so next-head rq (L2 ~200cy) + kb (LDS ~120cy)
//   latency hides under current head's ~400cy compute. RA runs post-sched,
//   so the prefetched values MUST stay live (+~24 VGPR — that rise is the
//   confirmation signal; 84 again = fences defeated too).
// Occupancy is NOT the lever: invariant ~29% across 3/4/5-block LDS configs.
// launch_bounds (256,3): (256,4) previously triggered pathological 64-VGPR
//   alloc + spills. Tripwires: WRITE_SIZE == 65536 KB; VGPR 105-125.
__global__ __launch_bounds__(256, 3) void attn_kernel(
    const float* __restrict__ x, const float* __restrict__ mask,
    const float* __restrict__ qkv_b, const float* __restrict__ proj_b,
    const float* __restrict__ ws, float* __restrict__ out)
{
  __shared__ __attribute__((aligned(16))) __bf16 sK [64 * 128];  // 16384 B, swizzled
  __shared__ __attribute__((aligned(16))) __bf16 sVT[128 * 64];  // 16384 B, swizzled
  // total 32768 B

#define SKI(row, col) ((row)*128 + ((col) ^ (((row)&3)<<4) ^ ((row)&4)))
#define SVI(ch, tok)  ((ch)*64  + ((tok) ^ (((ch)&7)<<3)))
#define SBAR() __builtin_amdgcn_sched_barrier(0)

  const int w    = blockIdx.x;
  const int b    = w >> 10;
  const int tid  = threadIdx.x;
  const int wv   = tid >> 6;
  const int lane = tid & 63;
  const int quad = lane >> 4;
  const int l15  = lane & 15;
  const int row0 = wv * 16;

  // ---- A/B-fragments of x from global (fp32 -> bf16) ----
  bf16x8 af[4][4];   // [mt][kt]
  {
    const float* xw = x + (size_t)w * 8192;
    #pragma unroll
    for (int mt = 0; mt < 4; ++mt)
      #pragma unroll
      for (int kt = 0; kt < 4; ++kt) {
        const float* p = xw + (mt*16 + l15) * 128 + kt*32 + quad*8;
        float4 f0 = *(const float4*)p;
        float4 f1 = *(const float4*)(p + 4);
        bf16x8 v;
        v[0]=(__bf16)f0.x; v[1]=(__bf16)f0.y; v[2]=(__bf16)f0.z; v[3]=(__bf16)f0.w;
        v[4]=(__bf16)f1.x; v[5]=(__bf16)f1.y; v[6]=(__bf16)f1.z; v[7]=(__bf16)f1.w;
        af[mt][kt] = v;
      }
  }

  const __bf16* wq = (const __bf16*)(ws + OFF_WQ);

  // ---- K,V slices: wave handles nt in {8+wv, 12+wv, 16+wv, 20+wv} over all mt ----
  {
    #pragma unroll
    for (int t = 0; t < 4; ++t) {
      const int nt = 8 + ((t >> 1) << 3) + ((t & 1) << 2) + wv;
      bf16x8 bfr[4];
      #pragma unroll
      for (int kt = 0; kt < 4; ++kt)
        bfr[kt] = *(const bf16x8*)(wq + ((size_t)(nt*4 + kt) * 64 + lane) * 8);
      const float bias = qkv_b[nt*16 + l15];
      const int col = nt*16 + l15;
      #pragma unroll
      for (int mt = 0; mt < 4; ++mt) {
        floatx4 acc = {bias, bias, bias, bias};
        #pragma unroll
        for (int kt = 0; kt < 4; ++kt)
          acc = __builtin_amdgcn_mfma_f32_16x16x32_bf16(af[mt][kt], bfr[kt], acc, 0, 0, 0);
        if (nt < 16) {          // K: sigma-permuted row placement, swizzled
          const int c = col - 128;
          const int srow0 = ((((quad & 1) << 1) + (mt >> 1)) << 4)
                          + ((((mt & 1) << 1) | (quad >> 1)) << 2);
          #pragma unroll
          for (int r = 0; r < 4; ++r) sK[SKI(srow0 + r, c)] = (__bf16)acc[r];
        } else {                // V, modulated, transposed (natural token order), swizzled
          const int c = col - 256;
          const float sp = ws[OFF_AFF + b*256 + c];
          const float bp = ws[OFF_AFF + b*256 + 128 + c];
          const int rowb = mt*16 + quad*4;
          #pragma unroll
          for (int r = 0; r < 4; ++r) sVT[SVI(c, rowb + r)] = (__bf16)fmaf(sp, acc[r], bp);
        }
      }
    }
  }

  // ---- Q^T GEMM into registers: own 16 tokens, all 8 head-slices ----
  bf16x8 aq[4];
  #pragma unroll
  for (int kt = 0; kt < 4; ++kt) aq[kt] = af[0][kt];
  #pragma unroll
  for (int mt = 1; mt < 4; ++mt)
    if (wv == mt) {
      #pragma unroll
      for (int kt = 0; kt < 4; ++kt) aq[kt] = af[mt][kt];
    }

  short4v qa[8];   // qa[h] = B-frag: Q[row0+l15][h*16+quad*4+j] * QSCALE
  {
    #pragma unroll
    for (int nt = 0; nt < 8; ++nt) {
      bf16x8 bfr[4];
      #pragma unroll
      for (int kt = 0; kt < 4; ++kt)
        bfr[kt] = *(const bf16x8*)(wq + ((size_t)(nt*4 + kt) * 64 + lane) * 8);
      floatx4 acc = *(const floatx4*)(qkv_b + nt*16 + quad*4);
      #pragma unroll
      for (int kt = 0; kt < 4; ++kt)
        acc = __builtin_amdgcn_mfma_f32_16x16x32_bf16(bfr[kt], aq[kt], acc, 0, 0, 0);
      union { short4v s; __bf16 h4[4]; } u;
      #pragma unroll
      for (int r = 0; r < 4; ++r) u.h4[r] = (__bf16)(acc[r] * QSCALE);
      qa[nt] = u.s;
    }
  }
  __syncthreads();   // the only barrier

  // ---- mask hoist (pre-scaled by log2e), float4 over r at sigma j-offsets ----
  floatx4 mv[4];
  {
    const float* mrow = mask + (size_t)(w & 1023) * 4096 + (row0 + l15) * 64;
    #pragma unroll
    for (int jt = 0; jt < 4; ++jt) {
      const int joff = ((jt & 1) << 5) + ((jt >> 1) << 2) + (quad << 3);
      floatx4 m4 = *(const floatx4*)(mrow + joff);
      #pragma unroll
      for (int r = 0; r < 4; ++r) mv[jt][r] = m4[r] * LOG2E;
    }
  }

  floatx4 pacc[8];
  #pragma unroll
  for (int nt = 0; nt < 8; ++nt) {
    float pb = proj_b[nt*16 + l15];
    pacc[nt] = (floatx4){pb, pb, pb, pb};
  }

  bf16x8 ones;
  #pragma unroll
  for (int i = 0; i < 8; ++i) ones[i] = (__bf16)1.0f;

  const float* rpb = ws + OFF_RPB;
  const __bf16* wp = (const __bf16*)(ws + OFF_WP);

  // ---- 2-deep pipelined head loop, fenced so prefetches cannot sink ----
#define HLOAD(H, RQ, KB) do {                                               \
    _Pragma("unroll")                                                       \
    for (int jt = 0; jt < 4; ++jt) {                                        \
      const int joff = ((jt & 1) << 5) + ((jt >> 1) << 2) + (quad << 3);    \
      RQ[jt] = *(const floatx4*)(rpb + (H)*4096 + (row0 + l15)*64 + joff);  \
      KB[jt] = *(const short4v*)(&sK[SKI(jt*16 + l15, (H)*16 + quad*4)]);   \
    }                                                                       \
  } while (0)

#define HCOMP(H, RQ, KB) do {                                               \
    short4v wpf[8];                                                         \
    _Pragma("unroll")                                                       \
    for (int nt = 0; nt < 8; ++nt)                                          \
      wpf[nt] = *(const short4v*)(wp + ((size_t)((H)*8 + nt)*64 + lane)*4); \
    floatx4 s_[4];                                                          \
    _Pragma("unroll")                                                       \
    for (int jt = 0; jt < 4; ++jt) {                                        \
      floatx4 ci = RQ[jt] + mv[jt];                                         \
      s_[jt] = __builtin_amdgcn_mfma_f32_16x16x16bf16_1k(KB[jt], qa[H], ci, 0, 0, 0); \
    }                                                                       \
    union { bf16x8 v; __bf16 e[8]; } p0, p1;                                \
    _Pragma("unroll")                                                       \
    for (int r = 0; r < 4; ++r) {                                           \
      p0.e[r]     = (__bf16)EXP2F(s_[0][r]);                                \
      p0.e[4 + r] = (__bf16)EXP2F(s_[2][r]);                                \
      p1.e[r]     = (__bf16)EXP2F(s_[1][r]);                                \
      p1.e[4 + r] = (__bf16)EXP2F(s_[3][r]);                                \
    }                                                                       \
    bf16x8 vb0 = *(const bf16x8*)(&sVT[SVI((H)*16 + l15, quad*8)]);         \
    bf16x8 vb1 = *(const bf16x8*)(&sVT[SVI((H)*16 + l15, 32 + quad*8)]);    \
    floatx4 o2 = {0.f,0.f,0.f,0.f}, sm_ = {0.f,0.f,0.f,0.f};                \
    o2  = __builtin_amdgcn_mfma_f32_16x16x32_bf16(vb0, p0.v, o2, 0, 0, 0);  \
    sm_ = __builtin_amdgcn_mfma_f32_16x16x32_bf16(ones, p0.v, sm_, 0, 0, 0);\
    o2  = __builtin_amdgcn_mfma_f32_16x16x32_bf16(vb1, p1.v, o2, 0, 0, 0);  \
    sm_ = __builtin_amdgcn_mfma_f32_16x16x32_bf16(ones, p1.v, sm_, 0, 0, 0);\
    const float inv = 1.0f / sm_[0];                                        \
    union { short4v s; __bf16 hh_[4]; } u_;                                 \
    _Pragma("unroll")                                                       \
    for (int r = 0; r < 4; ++r) u_.hh_[r] = (__bf16)(o2[r] * inv);          \
    _Pragma("unroll")                                                       \
    for (int nt = 0; nt < 8; ++nt)                                          \
      pacc[nt] = __builtin_amdgcn_mfma_f32_16x16x16bf16_1k(u_.s, wpf[nt], pacc[nt], 0, 0, 0); \
  } while (0)

  {
    floatx4 rqA[4], rqB[4];
    short4v kbA[4], kbB[4];
    HLOAD(0, rqA, kbA);
    #pragma unroll 1
    for (int hh = 0; hh < 4; ++hh) {
      const int h0 = hh * 2;
      SBAR();
      HLOAD(h0 + 1, rqB, kbB);      // prefetch odd head
      SBAR();                        // loads above may not sink below
      HCOMP(h0, rqA, kbA);
      SBAR();
      if (hh < 3) HLOAD(h0 + 2, rqA, kbA);   // prefetch next even head
      SBAR();                        // loads above may not sink below
      HCOMP(h0 + 1, rqB, kbB);
    }
  }
#undef HLOAD
#undef HCOMP

  // ---- store ----
  {
    float* ow = out + (size_t)w * 8192;
    #pragma unroll
    for (int nt = 0; nt < 8; ++nt)
      #pragma unroll
      for (int r = 0; r < 4; ++r)
        ow[(row0 + quad*4 + r)*128 + nt*16 + l15] = pacc[nt][r];
  }
#undef SKI
#undef SVI
#undef SBAR
}

extern "C" void kernel_launch(void* const* d_in, const int* in_sizes, int n_in,
                              void* d_out, int out_size, void* d_ws, size_t ws_size,
                              hipStream_t stream)
{
  const float* x          = (const float*)d_in[0];
  const float* mask       = (const float*)d_in[1];
  const float* frame_type = (const float*)d_in[2];
  const float* qkv_w      = (const float*)d_in[3];
  const float* qkv_b      = (const float*)d_in[4];
  const float* table      = (const float*)d_in[5];
  const float* proj_w     = (const float*)d_in[6];
  const float* proj_b     = (const float*)d_in[7];
  const float* aff_w1     = (const float*)d_in[8];
  const float* aff_b1     = (const float*)d_in[9];
  const float* aff_w2     = (const float*)d_in[10];
  const int*   rel_index  = (const int*)d_in[11];
  float* ws   = (float*)d_ws;
  float* outp = (float*)d_out;

  prep_kernel<<<192, 256, 0, stream>>>(frame_type, qkv_w, table, proj_w,
                                       aff_w1, aff_b1, aff_w2, rel_index, ws);
  attn_kernel<<<NWIN, 256, 0, stream>>>(x, mask, qkv_b, proj_b, ws, outp);
}

// Round 9
// 218.586 us; speedup vs baseline: 1.0447x; 1.0243x over previous
//
#include <hip/hip_runtime.h>
#include <hip/hip_bf16.h>

#define NWIN 2048
#define LOG2E 1.44269504f
#define QSCALE 0.36067376f   // 0.25 * log2(e)

// ws layout (float offsets)
#define OFF_AFF 0        // 512 floats: [b][0..127]=softplus(scale), [128..255]=bias
#define OFF_RPB 512      // 32768 floats: rpb[h][row][col] * LOG2E  (natural, float4-loadable)
#define OFF_WQ  33280    // 49152 bf16 (24576 floats): qkv_w packed frags (16x16x32)
#define OFF_WP  57856    // 16384 bf16 (8192 floats): proj_w packed B-frags (16x16x16)

typedef __attribute__((ext_vector_type(8))) __bf16 bf16x8;
typedef __attribute__((ext_vector_type(4))) float floatx4;
typedef __attribute__((ext_vector_type(4))) short short4v;

#if __has_builtin(__builtin_amdgcn_exp2f)
#define EXP2F __builtin_amdgcn_exp2f
#else
#define EXP2F exp2f
#endif
#if __has_builtin(__builtin_amdgcn_rcpf)
#define RCPF __builtin_amdgcn_rcpf
#else
#define RCPF(x) (1.0f / (x))
#endif

__global__ __launch_bounds__(256) void prep_kernel(
    const float* __restrict__ frame_type, const float* __restrict__ qkv_w,
    const float* __restrict__ table, const float* __restrict__ proj_w,
    const float* __restrict__ aff_w1, const float* __restrict__ aff_b1,
    const float* __restrict__ aff_w2, const int* __restrict__ rel_index,
    float* __restrict__ ws)
{
  const int gid = blockIdx.x * 256 + threadIdx.x;   // grid covers 49152
  // pack qkv_w into 16x16x32 frag order: idx = ((nt*4+kt)*64+lane)*8+j
  if (gid < 49152) {
    int j = gid & 7, lane = (gid >> 3) & 63, kt = (gid >> 9) & 3, nt = gid >> 11;
    int n = nt * 16 + (lane & 15);
    int k = kt * 32 + (lane >> 4) * 8 + j;
    ((__bf16*)(ws + OFF_WQ))[gid] = (__bf16)qkv_w[n * 128 + k];
  }
  // pack proj_w into 16x16x16 B-frag order: idx = ((h*8+nt)*64+lane)*4+j
  if (gid < 16384) {
    int j = gid & 3, lane = (gid >> 2) & 63, nt = (gid >> 8) & 7, h = gid >> 11;
    int n = nt * 16 + (lane & 15);
    int k = h * 16 + (lane >> 4) * 4 + j;
    ((__bf16*)(ws + OFF_WP))[gid] = (__bf16)proj_w[n * 128 + k];
  }
  // rpb natural [h][row][col] layout, pre-scaled by log2(e)
  if (gid < 32768) {
    int h = gid >> 12, rem = gid & 4095;
    ws[OFF_RPB + gid] = table[rel_index[rem] * 8 + h] * LOG2E;
  }
  // affine params
  if (gid < 512) {
    int b = gid >> 8, c2 = gid & 255;
    float hd[16];
    #pragma unroll
    for (int j = 0; j < 16; ++j) {
      float t = frame_type[b*2+0]*aff_w1[j*2+0] + frame_type[b*2+1]*aff_w1[j*2+1] + aff_b1[j];
      hd[j] = 1.0f / (1.0f + expf(-t));
    }
    float ap = 0.f;
    #pragma unroll
    for (int j = 0; j < 16; ++j) ap += hd[j] * aff_w2[c2*16 + j];
    float r = (c2 < 128) ? ((ap > 20.f) ? ap : log1pf(expf(ap))) : ap;
    ws[OFF_AFF + gid] = r;
  }
}

// Swapped-QK^T structure (validated round 3):
//   S^T = mfma(K_slot, Q^T): lane holds S[q=row0+l15][j=sigma(jt,quad,r)]
//   sigma(jt,quad,r) = 32*(jt&1) + 8*quad + 4*(jt>>1) + r
//   K sigma-permuted in sK; V^T natural; exp2'd scores pack IN-LANE into the
//   PV B-frag; Q^T per-wave in registers. One barrier, LDS 32768 B.
// Round-9 changes (round-8 fences REVERTED — they cost 10% without
//   materializing the pipeline; VGPR stayed 84):
//   (1) PROJ DEFERRED out of the head loop. Phase A (8x unrolled, named
//       u0..u7 — no dynamic reg indexing) computes QK->exp2->PV->normalize
//       into 2 regs/head; phase B does all 64 proj MFMAs with 8 independent
//       accumulators and per-head wpf bursts. Removes 8 L2 loads + 8
//       dependent MFMAs from every head's serial chain.
//   (2) v_rcp_f32 for 1/rowsum: the exact divide is ~10 serial insts ON the
//       chain; rcp is 1 (rel err 1e-7, invisible under bf16 rounding).
// Cross-round finding: bench dur ~= COLD attn (x/mask not L3-resident);
//   cold tracks warm + traffic/achieved-BW, both set by dependency stalls.
// Tripwires: WRITE_SIZE == 65536 KB (spill); VGPR expected ~95-125.
__global__ __launch_bounds__(256, 3) void attn_kernel(
    const float* __restrict__ x, const float* __restrict__ mask,
    const float* __restrict__ qkv_b, const float* __restrict__ proj_b,
    const float* __restrict__ ws, float* __restrict__ out)
{
  __shared__ __attribute__((aligned(16))) __bf16 sK [64 * 128];  // 16384 B, swizzled
  __shared__ __attribute__((aligned(16))) __bf16 sVT[128 * 64];  // 16384 B, swizzled
  // total 32768 B

#define SKI(row, col) ((row)*128 + ((col) ^ (((row)&3)<<4) ^ ((row)&4)))
#define SVI(ch, tok)  ((ch)*64  + ((tok) ^ (((ch)&7)<<3)))

  const int w    = blockIdx.x;
  const int b    = w >> 10;
  const int tid  = threadIdx.x;
  const int wv   = tid >> 6;
  const int lane = tid & 63;
  const int quad = lane >> 4;
  const int l15  = lane & 15;
  const int row0 = wv * 16;

  // ---- A/B-fragments of x from global (fp32 -> bf16) ----
  bf16x8 af[4][4];   // [mt][kt]
  {
    const float* xw = x + (size_t)w * 8192;
    #pragma unroll
    for (int mt = 0; mt < 4; ++mt)
      #pragma unroll
      for (int kt = 0; kt < 4; ++kt) {
        const float* p = xw + (mt*16 + l15) * 128 + kt*32 + quad*8;
        float4 f0 = *(const float4*)p;
        float4 f1 = *(const float4*)(p + 4);
        bf16x8 v;
        v[0]=(__bf16)f0.x; v[1]=(__bf16)f0.y; v[2]=(__bf16)f0.z; v[3]=(__bf16)f0.w;
        v[4]=(__bf16)f1.x; v[5]=(__bf16)f1.y; v[6]=(__bf16)f1.z; v[7]=(__bf16)f1.w;
        af[mt][kt] = v;
      }
  }

  const __bf16* wq = (const __bf16*)(ws + OFF_WQ);

  // ---- K,V slices: wave handles nt in {8+wv, 12+wv, 16+wv, 20+wv} over all mt ----
  {
    #pragma unroll
    for (int t = 0; t < 4; ++t) {
      const int nt = 8 + ((t >> 1) << 3) + ((t & 1) << 2) + wv;
      bf16x8 bfr[4];
      #pragma unroll
      for (int kt = 0; kt < 4; ++kt)
        bfr[kt] = *(const bf16x8*)(wq + ((size_t)(nt*4 + kt) * 64 + lane) * 8);
      const float bias = qkv_b[nt*16 + l15];
      const int col = nt*16 + l15;
      #pragma unroll
      for (int mt = 0; mt < 4; ++mt) {
        floatx4 acc = {bias, bias, bias, bias};
        #pragma unroll
        for (int kt = 0; kt < 4; ++kt)
          acc = __builtin_amdgcn_mfma_f32_16x16x32_bf16(af[mt][kt], bfr[kt], acc, 0, 0, 0);
        if (nt < 16) {          // K: sigma-permuted row placement, swizzled
          const int c = col - 128;
          const int srow0 = ((((quad & 1) << 1) + (mt >> 1)) << 4)
                          + ((((mt & 1) << 1) | (quad >> 1)) << 2);
          #pragma unroll
          for (int r = 0; r < 4; ++r) sK[SKI(srow0 + r, c)] = (__bf16)acc[r];
        } else {                // V, modulated, transposed (natural token order), swizzled
          const int c = col - 256;
          const float sp = ws[OFF_AFF + b*256 + c];
          const float bp = ws[OFF_AFF + b*256 + 128 + c];
          const int rowb = mt*16 + quad*4;
          #pragma unroll
          for (int r = 0; r < 4; ++r) sVT[SVI(c, rowb + r)] = (__bf16)fmaf(sp, acc[r], bp);
        }
      }
    }
  }

  // ---- Q^T GEMM into registers: own 16 tokens, all 8 head-slices ----
  bf16x8 aq[4];
  #pragma unroll
  for (int kt = 0; kt < 4; ++kt) aq[kt] = af[0][kt];
  #pragma unroll
  for (int mt = 1; mt < 4; ++mt)
    if (wv == mt) {
      #pragma unroll
      for (int kt = 0; kt < 4; ++kt) aq[kt] = af[mt][kt];
    }

  short4v qa[8];   // qa[h] = B-frag: Q[row0+l15][h*16+quad*4+j] * QSCALE
  {
    #pragma unroll
    for (int nt = 0; nt < 8; ++nt) {
      bf16x8 bfr[4];
      #pragma unroll
      for (int kt = 0; kt < 4; ++kt)
        bfr[kt] = *(const bf16x8*)(wq + ((size_t)(nt*4 + kt) * 64 + lane) * 8);
      floatx4 acc = *(const floatx4*)(qkv_b + nt*16 + quad*4);
      #pragma unroll
      for (int kt = 0; kt < 4; ++kt)
        acc = __builtin_amdgcn_mfma_f32_16x16x32_bf16(bfr[kt], aq[kt], acc, 0, 0, 0);
      union { short4v s; __bf16 h4[4]; } u;
      #pragma unroll
      for (int r = 0; r < 4; ++r) u.h4[r] = (__bf16)(acc[r] * QSCALE);
      qa[nt] = u.s;
    }
  }
  __syncthreads();   // the only barrier

  // ---- mask hoist (pre-scaled by log2e), float4 over r at sigma j-offsets ----
  floatx4 mv[4];
  {
    const float* mrow = mask + (size_t)(w & 1023) * 4096 + (row0 + l15) * 64;
    #pragma unroll
    for (int jt = 0; jt < 4; ++jt) {
      const int joff = ((jt & 1) << 5) + ((jt >> 1) << 2) + (quad << 3);
      floatx4 m4 = *(const floatx4*)(mrow + joff);
      #pragma unroll
      for (int r = 0; r < 4; ++r) mv[jt][r] = m4[r] * LOG2E;
    }
  }

  bf16x8 ones;
  #pragma unroll
  for (int i = 0; i < 8; ++i) ones[i] = (__bf16)1.0f;

  const float* rpb = ws + OFF_RPB;
  const __bf16* wp = (const __bf16*)(ws + OFF_WP);

  // ---- Phase A: per-head QK^T -> exp2 in-lane -> PV -> normalize -> u (2 regs) ----
#define PHASEA(H, U) do {                                                   \
    floatx4 rq_[4];                                                         \
    short4v kb_[4];                                                         \
    _Pragma("unroll")                                                       \
    for (int jt = 0; jt < 4; ++jt) {                                        \
      const int joff = ((jt & 1) << 5) + ((jt >> 1) << 2) + (quad << 3);    \
      rq_[jt] = *(const floatx4*)(rpb + (H)*4096 + (row0 + l15)*64 + joff); \
      kb_[jt] = *(const short4v*)(&sK[SKI(jt*16 + l15, (H)*16 + quad*4)]);  \
    }                                                                       \
    floatx4 s_[4];                                                          \
    _Pragma("unroll")                                                       \
    for (int jt = 0; jt < 4; ++jt) {                                        \
      floatx4 ci = rq_[jt] + mv[jt];                                        \
      s_[jt] = __builtin_amdgcn_mfma_f32_16x16x16bf16_1k(kb_[jt], qa[H], ci, 0, 0, 0); \
    }                                                                       \
    union { bf16x8 v; __bf16 e[8]; } p0_, p1_;                              \
    _Pragma("unroll")                                                       \
    for (int r = 0; r < 4; ++r) {                                           \
      p0_.e[r]     = (__bf16)EXP2F(s_[0][r]);                               \
      p0_.e[4 + r] = (__bf16)EXP2F(s_[2][r]);                               \
      p1_.e[r]     = (__bf16)EXP2F(s_[1][r]);                               \
      p1_.e[4 + r] = (__bf16)EXP2F(s_[3][r]);                               \
    }                                                                       \
    bf16x8 vb0 = *(const bf16x8*)(&sVT[SVI((H)*16 + l15, quad*8)]);         \
    bf16x8 vb1 = *(const bf16x8*)(&sVT[SVI((H)*16 + l15, 32 + quad*8)]);    \
    floatx4 o2 = {0.f,0.f,0.f,0.f}, sm_ = {0.f,0.f,0.f,0.f};                \
    o2  = __builtin_amdgcn_mfma_f32_16x16x32_bf16(vb0, p0_.v, o2, 0, 0, 0); \
    sm_ = __builtin_amdgcn_mfma_f32_16x16x32_bf16(ones, p0_.v, sm_, 0, 0, 0);\
    o2  = __builtin_amdgcn_mfma_f32_16x16x32_bf16(vb1, p1_.v, o2, 0, 0, 0); \
    sm_ = __builtin_amdgcn_mfma_f32_16x16x32_bf16(ones, p1_.v, sm_, 0, 0, 0);\
    const float inv = RCPF(sm_[0]);                                         \
    union { short4v s; __bf16 hh_[4]; } u_;                                 \
    _Pragma("unroll")                                                       \
    for (int r = 0; r < 4; ++r) u_.hh_[r] = (__bf16)(o2[r] * inv);          \
    U = u_.s;                                                               \
  } while (0)

  short4v u0, u1, u2, u3, u4, u5, u6, u7;
  PHASEA(0, u0); PHASEA(1, u1); PHASEA(2, u2); PHASEA(3, u3);
  PHASEA(4, u4); PHASEA(5, u5); PHASEA(6, u6); PHASEA(7, u7);
#undef PHASEA

  // ---- Phase B: proj GEMM — all 64 MFMAs, 8 independent accumulators ----
  floatx4 pacc[8];
  #pragma unroll
  for (int nt = 0; nt < 8; ++nt) {
    float pb = proj_b[nt*16 + l15];
    pacc[nt] = (floatx4){pb, pb, pb, pb};
  }

#define PHASEB(H, U) do {                                                   \
    short4v wpf_[8];                                                        \
    _Pragma("unroll")                                                       \
    for (int nt = 0; nt < 8; ++nt)                                          \
      wpf_[nt] = *(const short4v*)(wp + ((size_t)((H)*8 + nt)*64 + lane)*4);\
    _Pragma("unroll")                                                       \
    for (int nt = 0; nt < 8; ++nt)                                          \
      pacc[nt] = __builtin_amdgcn_mfma_f32_16x16x16bf16_1k(U, wpf_[nt], pacc[nt], 0, 0, 0); \
  } while (0)

  PHASEB(0, u0); PHASEB(1, u1); PHASEB(2, u2); PHASEB(3, u3);
  PHASEB(4, u4); PHASEB(5, u5); PHASEB(6, u6); PHASEB(7, u7);
#undef PHASEB

  // ---- store ----
  {
    float* ow = out + (size_t)w * 8192;
    #pragma unroll
    for (int nt = 0; nt < 8; ++nt)
      #pragma unroll
      for (int r = 0; r < 4; ++r)
        ow[(row0 + quad*4 + r)*128 + nt*16 + l15] = pacc[nt][r];
  }
#undef SKI
#undef SVI
}

extern "C" void kernel_launch(void* const* d_in, const int* in_sizes, int n_in,
                              void* d_out, int out_size, void* d_ws, size_t ws_size,
                              hipStream_t stream)
{
  const float* x          = (const float*)d_in[0];
  const float* mask       = (const float*)d_in[1];
  const float* frame_type = (const float*)d_in[2];
  const float* qkv_w      = (const float*)d_in[3];
  const float* qkv_b      = (const float*)d_in[4];
  const float* table      = (const float*)d_in[5];
  const float* proj_w     = (const float*)d_in[6];
  const float* proj_b     = (const float*)d_in[7];
  const float* aff_w1     = (const float*)d_in[8];
  const float* aff_b1     = (const float*)d_in[9];
  const float* aff_w2     = (const float*)d_in[10];
  const int*   rel_index  = (const int*)d_in[11];
  float* ws   = (float*)d_ws;
  float* outp = (float*)d_out;

  prep_kernel<<<192, 256, 0, stream>>>(frame_type, qkv_w, table, proj_w,
                                       aff_w1, aff_b1, aff_w2, rel_index, ws);
  attn_kernel<<<NWIN, 256, 0, stream>>>(x, mask, qkv_b, proj_b, ws, outp);
}

// Round 10
// 203.905 us; speedup vs baseline: 1.1199x; 1.0720x over previous
//
#include <hip/hip_runtime.h>
#include <hip/hip_bf16.h>

#define LOG2E 1.44269504f
#define QSCALE 0.36067376f   // 0.25 * log2(e)

// ws layout (float offsets)
#define OFF_AFF 0        // 512 floats: [b][0..127]=softplus(scale), [128..255]=bias
#define OFF_RPB 512      // 32768 floats: rpb[h][row][col] * LOG2E  (natural, float4-loadable)
#define OFF_WQ  33280    // 49152 bf16 (24576 floats): qkv_w packed frags (16x16x32)
#define OFF_WP  57856    // 16384 bf16 (8192 floats): proj_w packed B-frags (16x16x16)

typedef __attribute__((ext_vector_type(8))) __bf16 bf16x8;
typedef __attribute__((ext_vector_type(4))) float floatx4;
typedef __attribute__((ext_vector_type(4))) short short4v;

#if __has_builtin(__builtin_amdgcn_exp2f)
#define EXP2F __builtin_amdgcn_exp2f
#else
#define EXP2F exp2f
#endif
#if __has_builtin(__builtin_amdgcn_rcpf)
#define RCPF __builtin_amdgcn_rcpf
#else
#define RCPF(x) (1.0f / (x))
#endif

__global__ __launch_bounds__(256) void prep_kernel(
    const float* __restrict__ frame_type, const float* __restrict__ qkv_w,
    const float* __restrict__ table, const float* __restrict__ proj_w,
    const float* __restrict__ aff_w1, const float* __restrict__ aff_b1,
    const float* __restrict__ aff_w2, const int* __restrict__ rel_index,
    float* __restrict__ ws)
{
  const int gid = blockIdx.x * 256 + threadIdx.x;   // grid covers 49152
  // pack qkv_w into 16x16x32 frag order: idx = ((nt*4+kt)*64+lane)*8+j
  if (gid < 49152) {
    int j = gid & 7, lane = (gid >> 3) & 63, kt = (gid >> 9) & 3, nt = gid >> 11;
    int n = nt * 16 + (lane & 15);
    int k = kt * 32 + (lane >> 4) * 8 + j;
    ((__bf16*)(ws + OFF_WQ))[gid] = (__bf16)qkv_w[n * 128 + k];
  }
  // pack proj_w into 16x16x16 B-frag order: idx = ((h*8+nt)*64+lane)*4+j
  if (gid < 16384) {
    int j = gid & 3, lane = (gid >> 2) & 63, nt = (gid >> 8) & 7, h = gid >> 11;
    int n = nt * 16 + (lane & 15);
    int k = h * 16 + (lane >> 4) * 4 + j;
    ((__bf16*)(ws + OFF_WP))[gid] = (__bf16)proj_w[n * 128 + k];
  }
  // rpb natural [h][row][col] layout, pre-scaled by log2(e)
  if (gid < 32768) {
    int h = gid >> 12, rem = gid & 4095;
    ws[OFF_RPB + gid] = table[rel_index[rem] * 8 + h] * LOG2E;
  }
  // affine params
  if (gid < 512) {
    int b = gid >> 8, c2 = gid & 255;
    float hd[16];
    #pragma unroll
    for (int j = 0; j < 16; ++j) {
      float t = frame_type[b*2+0]*aff_w1[j*2+0] + frame_type[b*2+1]*aff_w1[j*2+1] + aff_b1[j];
      hd[j] = 1.0f / (1.0f + expf(-t));
    }
    float ap = 0.f;
    #pragma unroll
    for (int j = 0; j < 16; ++j) ap += hd[j] * aff_w2[c2*16 + j];
    float r = (c2 < 128) ? ((ap > 20.f) ? ap : log1pf(expf(ap))) : ap;
    ws[OFF_AFF + gid] = r;
  }
}

// Swapped-QK^T structure (validated rounds 3-9) + round-10 WINDOW PAIRING:
//   Each block processes windows (w, w+1024). Rationale: per-block L2 reads
//   of shared params (rpb 128KB + wq ~190KB + wp 32KB ≈ 350KB/block) were
//   10x the per-window input — the same wave now consumes every shared load
//   (bfr/rq/wpf/mv) TWICE, halving L2 traffic per window and doubling
//   per-wave ILP with chains that share operands (can't be serialized away
//   cheaply, unlike rounds 4/7/8's attempts).
//   mask[w&1023] is IDENTICAL for the pair -> mv loaded once.
//   Affine differs (b=0 vs b=1) -> two sp/bp loads.
// LDS 65536 B (2 windows) -> 2 blocks/CU static; effective occupancy has
//   been pinned ~9 waves/CU regardless of static limit (rounds 0-9), so the
//   residency loss is small vs 2x ILP + halved traffic.
// launch_bounds (256,2): LDS caps at 2 blocks/CU anyway -> up to 256 VGPR
//   free. Staging peak (afA+afB live) ~180.
// Proj deferred (round 9) + rcp for 1/rowsum (round 9) kept.
// Tripwires: WRITE_SIZE == 65536 KB (spill); VGPR expected 150-210.
__global__ __launch_bounds__(256, 2) void attn_kernel(
    const float* __restrict__ x, const float* __restrict__ mask,
    const float* __restrict__ qkv_b, const float* __restrict__ proj_b,
    const float* __restrict__ ws, float* __restrict__ out)
{
  __shared__ __attribute__((aligned(16))) __bf16 sK [2][64 * 128];  // 2x16384 B, swizzled
  __shared__ __attribute__((aligned(16))) __bf16 sVT[2][128 * 64];  // 2x16384 B, swizzled
  // total 65536 B

#define SKI(row, col) ((row)*128 + ((col) ^ (((row)&3)<<4) ^ ((row)&4)))
#define SVI(ch, tok)  ((ch)*64  + ((tok) ^ (((ch)&7)<<3)))

  const int w    = blockIdx.x;        // window A; window B = w + 1024
  const int tid  = threadIdx.x;
  const int wv   = tid >> 6;
  const int lane = tid & 63;
  const int quad = lane >> 4;
  const int l15  = lane & 15;
  const int row0 = wv * 16;

  // ---- A-fragments of x for BOTH windows (fp32 -> bf16) ----
  bf16x8 afA[4][4], afB[4][4];   // [mt][kt]
  {
    const float* xA = x + (size_t)w * 8192;
    const float* xB = xA + (size_t)1024 * 8192;
    #pragma unroll
    for (int mt = 0; mt < 4; ++mt)
      #pragma unroll
      for (int kt = 0; kt < 4; ++kt) {
        const int off = (mt*16 + l15) * 128 + kt*32 + quad*8;
        float4 a0 = *(const float4*)(xA + off);
        float4 a1 = *(const float4*)(xA + off + 4);
        float4 b0 = *(const float4*)(xB + off);
        float4 b1 = *(const float4*)(xB + off + 4);
        bf16x8 va, vb;
        va[0]=(__bf16)a0.x; va[1]=(__bf16)a0.y; va[2]=(__bf16)a0.z; va[3]=(__bf16)a0.w;
        va[4]=(__bf16)a1.x; va[5]=(__bf16)a1.y; va[6]=(__bf16)a1.z; va[7]=(__bf16)a1.w;
        vb[0]=(__bf16)b0.x; vb[1]=(__bf16)b0.y; vb[2]=(__bf16)b0.z; vb[3]=(__bf16)b0.w;
        vb[4]=(__bf16)b1.x; vb[5]=(__bf16)b1.y; vb[6]=(__bf16)b1.z; vb[7]=(__bf16)b1.w;
        afA[mt][kt] = va;
        afB[mt][kt] = vb;
      }
  }

  const __bf16* wq = (const __bf16*)(ws + OFF_WQ);

  // ---- K,V staging, both windows share each bfr load ----
  {
    #pragma unroll
    for (int t = 0; t < 4; ++t) {
      const int nt = 8 + ((t >> 1) << 3) + ((t & 1) << 2) + wv;
      bf16x8 bfr[4];
      #pragma unroll
      for (int kt = 0; kt < 4; ++kt)
        bfr[kt] = *(const bf16x8*)(wq + ((size_t)(nt*4 + kt) * 64 + lane) * 8);
      const float bias = qkv_b[nt*16 + l15];
      const int col = nt*16 + l15;
      #pragma unroll
      for (int mt = 0; mt < 4; ++mt) {
        floatx4 accA = {bias, bias, bias, bias};
        floatx4 accB = {bias, bias, bias, bias};
        #pragma unroll
        for (int kt = 0; kt < 4; ++kt) {
          accA = __builtin_amdgcn_mfma_f32_16x16x32_bf16(afA[mt][kt], bfr[kt], accA, 0, 0, 0);
          accB = __builtin_amdgcn_mfma_f32_16x16x32_bf16(afB[mt][kt], bfr[kt], accB, 0, 0, 0);
        }
        if (nt < 16) {          // K: sigma-permuted row placement, swizzled
          const int c = col - 128;
          const int srow0 = ((((quad & 1) << 1) + (mt >> 1)) << 4)
                          + ((((mt & 1) << 1) | (quad >> 1)) << 2);
          #pragma unroll
          for (int r = 0; r < 4; ++r) {
            sK[0][SKI(srow0 + r, c)] = (__bf16)accA[r];
            sK[1][SKI(srow0 + r, c)] = (__bf16)accB[r];
          }
        } else {                // V, modulated (per-batch affine), transposed, swizzled
          const int c = col - 256;
          const float spA = ws[OFF_AFF + c];
          const float bpA = ws[OFF_AFF + 128 + c];
          const float spB = ws[OFF_AFF + 256 + c];
          const float bpB = ws[OFF_AFF + 384 + c];
          const int rowb = mt*16 + quad*4;
          #pragma unroll
          for (int r = 0; r < 4; ++r) {
            sVT[0][SVI(c, rowb + r)] = (__bf16)fmaf(spA, accA[r], bpA);
            sVT[1][SVI(c, rowb + r)] = (__bf16)fmaf(spB, accB[r], bpB);
          }
        }
      }
    }
  }

  // ---- Q^T GEMM into registers, both windows share each bfr load ----
  bf16x8 aqA[4], aqB[4];
  #pragma unroll
  for (int kt = 0; kt < 4; ++kt) { aqA[kt] = afA[0][kt]; aqB[kt] = afB[0][kt]; }
  #pragma unroll
  for (int mt = 1; mt < 4; ++mt)
    if (wv == mt) {
      #pragma unroll
      for (int kt = 0; kt < 4; ++kt) { aqA[kt] = afA[mt][kt]; aqB[kt] = afB[mt][kt]; }
    }

  short4v qaA[8], qaB[8];   // qa[h] = B-frag: Q[row0+l15][h*16+quad*4+j] * QSCALE
  {
    #pragma unroll
    for (int nt = 0; nt < 8; ++nt) {
      bf16x8 bfr[4];
      #pragma unroll
      for (int kt = 0; kt < 4; ++kt)
        bfr[kt] = *(const bf16x8*)(wq + ((size_t)(nt*4 + kt) * 64 + lane) * 8);
      floatx4 bias4 = *(const floatx4*)(qkv_b + nt*16 + quad*4);
      floatx4 accA = bias4, accB = bias4;
      #pragma unroll
      for (int kt = 0; kt < 4; ++kt) {
        accA = __builtin_amdgcn_mfma_f32_16x16x32_bf16(bfr[kt], aqA[kt], accA, 0, 0, 0);
        accB = __builtin_amdgcn_mfma_f32_16x16x32_bf16(bfr[kt], aqB[kt], accB, 0, 0, 0);
      }
      union { short4v s; __bf16 h4[4]; } uA, uB;
      #pragma unroll
      for (int r = 0; r < 4; ++r) {
        uA.h4[r] = (__bf16)(accA[r] * QSCALE);
        uB.h4[r] = (__bf16)(accB[r] * QSCALE);
      }
      qaA[nt] = uA.s;
      qaB[nt] = uB.s;
    }
  }
  __syncthreads();   // the only barrier

  // ---- mask hoist: SHARED by the pair (w and w+1024 use mask[w]) ----
  floatx4 mv[4];
  {
    const float* mrow = mask + (size_t)w * 4096 + (row0 + l15) * 64;
    #pragma unroll
    for (int jt = 0; jt < 4; ++jt) {
      const int joff = ((jt & 1) << 5) + ((jt >> 1) << 2) + (quad << 3);
      floatx4 m4 = *(const floatx4*)(mrow + joff);
      #pragma unroll
      for (int r = 0; r < 4; ++r) mv[jt][r] = m4[r] * LOG2E;
    }
  }

  bf16x8 ones;
  #pragma unroll
  for (int i = 0; i < 8; ++i) ones[i] = (__bf16)1.0f;

  const float* rpb = ws + OFF_RPB;
  const __bf16* wp = (const __bf16*)(ws + OFF_WP);

  // ---- Phase A: per head, both windows; rq/kb shared loads; u -> 2 regs each ----
#define PHASEA2(H, UA, UB) do {                                              \
    floatx4 rq_[4];                                                          \
    short4v kbA_[4], kbB_[4];                                                \
    _Pragma("unroll")                                                        \
    for (int jt = 0; jt < 4; ++jt) {                                         \
      const int joff = ((jt & 1) << 5) + ((jt >> 1) << 2) + (quad << 3);     \
      rq_[jt] = *(const floatx4*)(rpb + (H)*4096 + (row0 + l15)*64 + joff);  \
      kbA_[jt] = *(const short4v*)(&sK[0][SKI(jt*16 + l15, (H)*16 + quad*4)]);\
      kbB_[jt] = *(const short4v*)(&sK[1][SKI(jt*16 + l15, (H)*16 + quad*4)]);\
    }                                                                        \
    floatx4 sA_[4], sB_[4];                                                  \
    _Pragma("unroll")                                                        \
    for (int jt = 0; jt < 4; ++jt) {                                         \
      floatx4 ci = rq_[jt] + mv[jt];                                         \
      sA_[jt] = __builtin_amdgcn_mfma_f32_16x16x16bf16_1k(kbA_[jt], qaA[H], ci, 0, 0, 0); \
      sB_[jt] = __builtin_amdgcn_mfma_f32_16x16x16bf16_1k(kbB_[jt], qaB[H], ci, 0, 0, 0); \
    }                                                                        \
    union { bf16x8 v; __bf16 e[8]; } p0A_, p1A_, p0B_, p1B_;                 \
    _Pragma("unroll")                                                        \
    for (int r = 0; r < 4; ++r) {                                            \
      p0A_.e[r]     = (__bf16)EXP2F(sA_[0][r]);                              \
      p0A_.e[4 + r] = (__bf16)EXP2F(sA_[2][r]);                              \
      p1A_.e[r]     = (__bf16)EXP2F(sA_[1][r]);                              \
      p1A_.e[4 + r] = (__bf16)EXP2F(sA_[3][r]);                              \
      p0B_.e[r]     = (__bf16)EXP2F(sB_[0][r]);                              \
      p0B_.e[4 + r] = (__bf16)EXP2F(sB_[2][r]);                              \
      p1B_.e[r]     = (__bf16)EXP2F(sB_[1][r]);                              \
      p1B_.e[4 + r] = (__bf16)EXP2F(sB_[3][r]);                              \
    }                                                                        \
    bf16x8 vbA0 = *(const bf16x8*)(&sVT[0][SVI((H)*16 + l15, quad*8)]);      \
    bf16x8 vbA1 = *(const bf16x8*)(&sVT[0][SVI((H)*16 + l15, 32 + quad*8)]); \
    bf16x8 vbB0 = *(const bf16x8*)(&sVT[1][SVI((H)*16 + l15, quad*8)]);      \
    bf16x8 vbB1 = *(const bf16x8*)(&sVT[1][SVI((H)*16 + l15, 32 + quad*8)]); \
    floatx4 o2A = {0.f,0.f,0.f,0.f}, smA = {0.f,0.f,0.f,0.f};                \
    floatx4 o2B = {0.f,0.f,0.f,0.f}, smB = {0.f,0.f,0.f,0.f};                \
    o2A = __builtin_amdgcn_mfma_f32_16x16x32_bf16(vbA0, p0A_.v, o2A, 0, 0, 0);\
    o2B = __builtin_amdgcn_mfma_f32_16x16x32_bf16(vbB0, p0B_.v, o2B, 0, 0, 0);\
    smA = __builtin_amdgcn_mfma_f32_16x16x32_bf16(ones, p0A_.v, smA, 0, 0, 0);\
    smB = __builtin_amdgcn_mfma_f32_16x16x32_bf16(ones, p0B_.v, smB, 0, 0, 0);\
    o2A = __builtin_amdgcn_mfma_f32_16x16x32_bf16(vbA1, p1A_.v, o2A, 0, 0, 0);\
    o2B = __builtin_amdgcn_mfma_f32_16x16x32_bf16(vbB1, p1B_.v, o2B, 0, 0, 0);\
    smA = __builtin_amdgcn_mfma_f32_16x16x32_bf16(ones, p1A_.v, smA, 0, 0, 0);\
    smB = __builtin_amdgcn_mfma_f32_16x16x32_bf16(ones, p1B_.v, smB, 0, 0, 0);\
    const float invA = RCPF(smA[0]);                                         \
    const float invB = RCPF(smB[0]);                                         \
    union { short4v s; __bf16 hh_[4]; } uA_, uB_;                            \
    _Pragma("unroll")                                                        \
    for (int r = 0; r < 4; ++r) {                                            \
      uA_.hh_[r] = (__bf16)(o2A[r] * invA);                                  \
      uB_.hh_[r] = (__bf16)(o2B[r] * invB);                                  \
    }                                                                        \
    UA = uA_.s; UB = uB_.s;                                                  \
  } while (0)

  short4v uA0, uA1, uA2, uA3, uA4, uA5, uA6, uA7;
  short4v uB0, uB1, uB2, uB3, uB4, uB5, uB6, uB7;
  PHASEA2(0, uA0, uB0); PHASEA2(1, uA1, uB1);
  PHASEA2(2, uA2, uB2); PHASEA2(3, uA3, uB3);
  PHASEA2(4, uA4, uB4); PHASEA2(5, uA5, uB5);
  PHASEA2(6, uA6, uB6); PHASEA2(7, uA7, uB7);
#undef PHASEA2

  // ---- Phase B: proj GEMM for both windows; wpf loaded once per head ----
  floatx4 paccA[8], paccB[8];
  #pragma unroll
  for (int nt = 0; nt < 8; ++nt) {
    float pb = proj_b[nt*16 + l15];
    paccA[nt] = (floatx4){pb, pb, pb, pb};
    paccB[nt] = (floatx4){pb, pb, pb, pb};
  }

#define PHASEB2(H, UA, UB) do {                                              \
    short4v wpf_[8];                                                         \
    _Pragma("unroll")                                                        \
    for (int nt = 0; nt < 8; ++nt)                                           \
      wpf_[nt] = *(const short4v*)(wp + ((size_t)((H)*8 + nt)*64 + lane)*4); \
    _Pragma("unroll")                                                        \
    for (int nt = 0; nt < 8; ++nt) {                                         \
      paccA[nt] = __builtin_amdgcn_mfma_f32_16x16x16bf16_1k(UA, wpf_[nt], paccA[nt], 0, 0, 0); \
      paccB[nt] = __builtin_amdgcn_mfma_f32_16x16x16bf16_1k(UB, wpf_[nt], paccB[nt], 0, 0, 0); \
    }                                                                        \
  } while (0)

  PHASEB2(0, uA0, uB0); PHASEB2(1, uA1, uB1);
  PHASEB2(2, uA2, uB2); PHASEB2(3, uA3, uB3);
  PHASEB2(4, uA4, uB4); PHASEB2(5, uA5, uB5);
  PHASEB2(6, uA6, uB6); PHASEB2(7, uA7, uB7);
#undef PHASEB2

  // ---- store both windows ----
  {
    float* owA = out + (size_t)w * 8192;
    float* owB = owA + (size_t)1024 * 8192;
    #pragma unroll
    for (int nt = 0; nt < 8; ++nt)
      #pragma unroll
      for (int r = 0; r < 4; ++r) {
        const int off = (row0 + quad*4 + r)*128 + nt*16 + l15;
        owA[off] = paccA[nt][r];
        owB[off] = paccB[nt][r];
      }
  }
#undef SKI
#undef SVI
}

extern "C" void kernel_launch(void* const* d_in, const int* in_sizes, int n_in,
                              void* d_out, int out_size, void* d_ws, size_t ws_size,
                              hipStream_t stream)
{
  const float* x          = (const float*)d_in[0];
  const float* mask       = (const float*)d_in[1];
  const float* frame_type = (const float*)d_in[2];
  const float* qkv_w      = (const float*)d_in[3];
  const float* qkv_b      = (const float*)d_in[4];
  const float* table      = (const float*)d_in[5];
  const float* proj_w     = (const float*)d_in[6];
  const float* proj_b     = (const float*)d_in[7];
  const float* aff_w1     = (const float*)d_in[8];
  const float* aff_b1     = (const float*)d_in[9];
  const float* aff_w2     = (const float*)d_in[10];
  const int*   rel_index  = (const int*)d_in[11];
  float* ws   = (float*)d_ws;
  float* outp = (float*)d_out;

  prep_kernel<<<192, 256, 0, stream>>>(frame_type, qkv_w, table, proj_w,
                                       aff_w1, aff_b1, aff_w2, rel_index, ws);
  attn_kernel<<<1024, 256, 0, stream>>>(x, mask, qkv_b, proj_b, ws, outp);
}